// Round 3
// baseline (328.397 us; speedup 1.0000x reference)
//
#include <hip/hip_runtime.h>

#define EPS 1e-5f

typedef __attribute__((ext_vector_type(8))) short bfrag;   // 8 bf16 = 4 VGPR (MFMA A/B)
typedef __attribute__((ext_vector_type(4))) float ffrag;   // 4 f32 (MFMA C/D)

union BFU { int i[4]; bfrag v; };

__device__ __forceinline__ float wave_sum64(float v) {
    #pragma unroll
    for (int off = 32; off > 0; off >>= 1) v += __shfl_xor(v, off, 64);
    return v;
}
__device__ __forceinline__ float wave_max64(float v) {
    #pragma unroll
    for (int off = 32; off > 0; off >>= 1) v = fmaxf(v, __shfl_xor(v, off, 64));
    return v;
}

// round-to-nearest-even f32 -> bf16, packed pair (proven bit-twiddle path)
__device__ __forceinline__ int pk_bf16(float a, float b) {
    union { float f; unsigned u; } x, y;
    x.f = a; y.f = b;
    unsigned ra = (x.u + 0x7fffu + ((x.u >> 16) & 1u)) >> 16;
    unsigned rb = (y.u + 0x7fffu + ((y.u >> 16) & 1u)) >> 16;
    return (int)((rb << 16) | (ra & 0xffffu));
}

// Sum across lanes {t, t+16, t+32, t+48} (the 4 quads) — proven shfl_xor path.
__device__ __forceinline__ float qsum(float v) {
    v += __shfl_xor(v, 16, 64);
    v += __shfl_xor(v, 32, 64);
    return v;
}

__device__ __forceinline__ float celu1(float x) {
    return (x > 0.f) ? x : (__expf(x) - 1.f);
}

// ---------------- Kernel 1: node branch + sr/sc ----------------
__global__ __launch_bounds__(64) void node_kernel(
    const float* __restrict__ node, const float* __restrict__ ln1_g, const float* __restrict__ ln1_b,
    const float* __restrict__ Wn, const float* __restrict__ bn, const float* __restrict__ attn_A,
    float* __restrict__ h_out, float* __restrict__ sr_out, float* __restrict__ sc_out)
{
    const int row  = blockIdx.x;
    const int lane = threadIdx.x;

    float x = node[(long)row * 64 + lane];
    float mu  = wave_sum64(x) * (1.0f / 64.0f);
    float d   = x - mu;
    float var = wave_sum64(d * d) * (1.0f / 64.0f);
    float xln = d * rsqrtf(var + EPS) * ln1_g[lane] + ln1_b[lane];

    __shared__ float xs[64];
    xs[lane] = xln;
    __syncthreads();

    float acc = bn[lane];
    const float* wrow = Wn + lane * 64;
    #pragma unroll
    for (int f = 0; f < 64; ++f) acc = fmaf(xs[f], wrow[f], acc);
    h_out[(long)row * 64 + lane] = acc;

    const int xidx = lane & 15;
    float ar = 0.f, ac = 0.f;
    #pragma unroll
    for (int hh = 0; hh < 4; ++hh) {
        ar += attn_A[hh * 48 + xidx];
        ac += attn_A[hh * 48 + 16 + xidx];
    }
    float pr = acc * ar, pc = acc * ac;
    #pragma unroll
    for (int off = 8; off > 0; off >>= 1) {
        pr += __shfl_down(pr, off, 16);
        pc += __shfl_down(pc, off, 16);
    }
    if (xidx == 0) {
        const int head = lane >> 4;
        sr_out[(long)row * 4 + head] = pr;
        sc_out[(long)row * 4 + head] = pc;
    }
}

// ---------------- Kernel 2: edge MLP via MFMA ----------------
// mfma_f32_16x16x32_bf16: A[m=lane&15][k=quad*8+j], B[k=quad*8+j][n=lane&15],
// D[m=quad*4+reg][n=lane&15].
//
// KEY TRICK: A1 is loaded with ROW-PERMUTED We1 — A-matrix row m maps to
// We1 row 8*(m>>2)+(m&3)+4*mt. Then lane (q,t)'s D1 regs hold hidden units
// {8q+reg} (acc0) and {8q+4+reg} (acc1) of row t — exactly the units its B2
// fragment B[k=8q+j][n=t] needs. B2 is the lane's own celu outputs: the
// 8-shuffle + 4-cndmask B2 gather of the old version is eliminated entirely.
// Remaining shuffles per tile: 4 B1 gathers + 10 reduction xors.
__global__ __launch_bounds__(256, 4) void edge_kernel(
    const float* __restrict__ edge, const int* __restrict__ adj,
    const float* __restrict__ ln2_g, const float* __restrict__ ln2_b,
    const float* __restrict__ We1, const float* __restrict__ be1,
    const float* __restrict__ We2, const float* __restrict__ be2,
    const float* __restrict__ lne_g, const float* __restrict__ lne_b,
    const float* __restrict__ attn_A,
    float* __restrict__ e_out, float* __restrict__ adj_out, float* __restrict__ se_out)
{
    const int tid  = threadIdx.x;
    const int wave = tid >> 6;
    const int lane = tid & 63;
    const int q    = lane >> 4;       // quad 0..3
    const int t    = lane & 15;
    const long r0  = (long)blockIdx.x * 256 + wave * 64;   // wave's 64 rows
    const int  c4  = 4 * q;           // this lane's channel chunk

    // ---- per-lane constants ----
    const float4 g1  = *(const float4*)(ln2_g + c4);
    const float4 b1  = *(const float4*)(ln2_b + c4);
    const float4 gE  = *(const float4*)(lne_g + c4);
    const float4 bE  = *(const float4*)(lne_b + c4);
    const float4 vb2 = *(const float4*)(be2 + c4);
    const float4 vb1a = *(const float4*)(be1 + 8 * q);      // hidden units 8q+reg   (acc0)
    const float4 vb1b = *(const float4*)(be1 + 8 * q + 4);  // hidden units 8q+4+reg (acc1)
    float4 ae = make_float4(0.f, 0.f, 0.f, 0.f);
    #pragma unroll
    for (int hh = 0; hh < 4; ++hh) {
        float4 a = *(const float4*)(attn_A + hh * 48 + 32 + c4);
        ae.x += a.x; ae.y += a.y; ae.z += a.z; ae.w += a.w;
    }

    // ---- weight fragments (loaded once, VGPR-resident) ----
    BFU A1[2], A2;
    A1[0].i[0] = A1[0].i[1] = A1[0].i[2] = A1[0].i[3] = 0;
    A1[1].i[0] = A1[1].i[1] = A1[1].i[2] = A1[1].i[3] = 0;
    if (q < 2) {   // K=16 zero-padded to 32: quads 2,3 stay zero
        const int rr = 8 * (t >> 2) + (t & 3);   // permuted We1 row for A-row m=t
        #pragma unroll
        for (int mt = 0; mt < 2; ++mt) {
            const float* wp = We1 + (rr + 4 * mt) * 16 + 8 * q;
            float4 w0 = *(const float4*)(wp);
            float4 w1 = *(const float4*)(wp + 4);
            A1[mt].i[0] = pk_bf16(w0.x, w0.y);
            A1[mt].i[1] = pk_bf16(w0.z, w0.w);
            A1[mt].i[2] = pk_bf16(w1.x, w1.y);
            A1[mt].i[3] = pk_bf16(w1.z, w1.w);
        }
    }
    {
        const float* wp = We2 + t * 32 + 8 * q;
        float4 w0 = *(const float4*)(wp);
        float4 w1 = *(const float4*)(wp + 4);
        A2.i[0] = pk_bf16(w0.x, w0.y);
        A2.i[1] = pk_bf16(w0.z, w0.w);
        A2.i[2] = pk_bf16(w1.x, w1.y);
        A2.i[3] = pk_bf16(w1.z, w1.w);
    }

    const int srcA = ((q & 1) << 5) + t;   // B1 gather sources
    const int srcB = srcA + 16;

    #pragma unroll
    for (int nt = 0; nt < 4; ++nt) {
        const long R = r0 + 16 * nt + t;          // this lane's row for tile nt
        const float4 v = *(const float4*)(edge + R * 16 + c4);

        // LN over E=16 (row spread across 4 quads, 4 vals each)
        float s1 = v.x + v.y + v.z + v.w;
        float s2 = fmaf(v.x, v.x, fmaf(v.y, v.y, fmaf(v.z, v.z, v.w * v.w)));
        s1 = qsum(s1);
        s2 = qsum(s2);
        const float mu = s1 * (1.0f / 16.0f);
        float var = fmaxf(s2 * (1.0f / 16.0f) - mu * mu, 0.f);
        const float rs = rsqrtf(var + EPS);
        const float x0 = (v.x - mu) * rs * g1.x + b1.x;
        const float x1 = (v.y - mu) * rs * g1.y + b1.y;
        const float x2 = (v.z - mu) * rs * g1.z + b1.z;
        const float x3 = (v.w - mu) * rs * g1.w + b1.w;
        const int p0 = pk_bf16(x0, x1), p1 = pk_bf16(x2, x3);

        // B1 fragment: B[k=8q+j][n=t] = xln[row 16nt+t][ch 8q+j] (k>=16 -> A1=0)
        BFU B1;
        B1.i[0] = __shfl(p0, srcA, 64);
        B1.i[1] = __shfl(p1, srcA, 64);
        B1.i[2] = __shfl(p0, srcB, 64);
        B1.i[3] = __shfl(p1, srcB, 64);

        ffrag acc0 = { vb1a.x, vb1a.y, vb1a.z, vb1a.w };   // bias in C (permuted units)
        ffrag acc1 = { vb1b.x, vb1b.y, vb1b.z, vb1b.w };
        acc0 = __builtin_amdgcn_mfma_f32_16x16x32_bf16(A1[0].v, B1.v, acc0, 0, 0, 0);
        acc1 = __builtin_amdgcn_mfma_f32_16x16x32_bf16(A1[1].v, B1.v, acc1, 0, 0, 0);

        // celu + pack: lane holds units 8q..8q+7 of row t == its own B2 fragment
        BFU B2;
        B2.i[0] = pk_bf16(celu1(acc0[0]), celu1(acc0[1]));   // units 8q+0,1
        B2.i[1] = pk_bf16(celu1(acc0[2]), celu1(acc0[3]));   // units 8q+2,3
        B2.i[2] = pk_bf16(celu1(acc1[0]), celu1(acc1[1]));   // units 8q+4,5
        B2.i[3] = pk_bf16(celu1(acc1[2]), celu1(acc1[3]));   // units 8q+6,7

        ffrag acc2 = { vb2.x, vb2.y, vb2.z, vb2.w };
        acc2 = __builtin_amdgcn_mfma_f32_16x16x32_bf16(A2.v, B2.v, acc2, 0, 0, 0);

        // residual + final LN + se
        const float o0 = acc2[0] + v.x;
        const float o1 = acc2[1] + v.y;
        const float o2 = acc2[2] + v.z;
        const float o3 = acc2[3] + v.w;
        float m1 = o0 + o1 + o2 + o3;
        float m2 = fmaf(o0, o0, fmaf(o1, o1, fmaf(o2, o2, o3 * o3)));
        m1 = qsum(m1);
        m2 = qsum(m2);
        const float mu2 = m1 * (1.0f / 16.0f);
        float var2 = fmaxf(m2 * (1.0f / 16.0f) - mu2 * mu2, 0.f);
        const float rs2 = rsqrtf(var2 + EPS);
        const float e0 = (o0 - mu2) * rs2 * gE.x + bE.x;
        const float e1 = (o1 - mu2) * rs2 * gE.y + bE.y;
        const float e2 = (o2 - mu2) * rs2 * gE.z + bE.z;
        const float e3 = (o3 - mu2) * rs2 * gE.w + bE.w;

        *(float4*)(e_out + R * 16 + c4) = make_float4(e0, e1, e2, e3);

        float sep = fmaf(e0, ae.x, fmaf(e1, ae.y, fmaf(e2, ae.z, e3 * ae.w)));
        sep = qsum(sep);
        if (q == 0) se_out[R] = sep;
    }

    // adj passthrough: one row per lane
    adj_out[r0 + lane] = (float)adj[r0 + lane];
}

// ---------------- Kernel 3: attention softmax + msg + output proj + LN ----------------
#define G 4
__global__ __launch_bounds__(256, 4) void attn_kernel(
    const float* __restrict__ h_ws, const float* __restrict__ sr_ws, const float* __restrict__ sc_ws,
    const float* __restrict__ se_ws, const int* __restrict__ adj,
    const float* __restrict__ node, const float* __restrict__ Wo, const float* __restrict__ bo,
    const float* __restrict__ lno_g, const float* __restrict__ lno_b,
    float* __restrict__ out)
{
    const int bi0  = blockIdx.x * G;
    const int b    = bi0 >> 9;
    const int tid  = threadIdx.x;
    const int wave = tid >> 6;
    const int lane = tid & 63;

    __shared__ __align__(16) float coef[G][4][516];
    __shared__ float hpart[4][G][64];
    __shared__ float msg_s[G][64];

    const float4* sc4 = (const float4*)(sc_ws + (long)b * 512 * 4);

    #pragma unroll
    for (int r = 0; r < G; ++r) {
        const int row = bi0 + r;
        const float sr0 = sr_ws[(long)row * 4 + 0];
        const float sr1 = sr_ws[(long)row * 4 + 1];
        const float sr2 = sr_ws[(long)row * 4 + 2];
        const float sr3 = sr_ws[(long)row * 4 + 3];
        const float* se_row  = se_ws + (long)row * 512;
        const int*   adj_row = adj   + (long)row * 512;
        #pragma unroll
        for (int half = 0; half < 2; ++half) {
            const int j = half * 256 + tid;
            float4 s = sc4[j];
            float  se = se_row[j];
            bool   m  = (adj_row[j] != 0);
            float l0 = m ? (sr0 + s.x + se) : -1e9f;
            float l1 = m ? (sr1 + s.y + se) : -1e9f;
            float l2 = m ? (sr2 + s.z + se) : -1e9f;
            float l3 = m ? (sr3 + s.w + se) : -1e9f;
            l0 = (l0 > 0.f) ? l0 : 0.2f * l0;  l0 = fminf(fmaxf(l0, -1e9f), 1e9f);
            l1 = (l1 > 0.f) ? l1 : 0.2f * l1;  l1 = fminf(fmaxf(l1, -1e9f), 1e9f);
            l2 = (l2 > 0.f) ? l2 : 0.2f * l2;  l2 = fminf(fmaxf(l2, -1e9f), 1e9f);
            l3 = (l3 > 0.f) ? l3 : 0.2f * l3;  l3 = fminf(fmaxf(l3, -1e9f), 1e9f);
            coef[r][0][j] = l0; coef[r][1][j] = l1; coef[r][2][j] = l2; coef[r][3][j] = l3;
        }
    }
    __syncthreads();

    // softmax: each lane owns a contiguous 8-float chunk -> 4 ds_read_b128 / lane
    #pragma unroll
    for (int qq = 0; qq < 4; ++qq) {
        const int p = qq * 4 + wave;
        float* L = coef[p >> 2][p & 3];
        float4 va = *(const float4*)&L[lane * 8];
        float4 vb = *(const float4*)&L[lane * 8 + 4];
        float m = fmaxf(fmaxf(fmaxf(va.x, va.y), fmaxf(va.z, va.w)),
                        fmaxf(fmaxf(vb.x, vb.y), fmaxf(vb.z, vb.w)));
        m = wave_max64(m);
        va.x = __expf(va.x - m); va.y = __expf(va.y - m);
        va.z = __expf(va.z - m); va.w = __expf(va.w - m);
        vb.x = __expf(vb.x - m); vb.y = __expf(vb.y - m);
        vb.z = __expf(vb.z - m); vb.w = __expf(vb.w - m);
        float s = (va.x + va.y + va.z + va.w) + (vb.x + vb.y + vb.z + vb.w);
        s = wave_sum64(s);
        const float inv = 1.0f / s;
        va.x *= inv; va.y *= inv; va.z *= inv; va.w *= inv;
        vb.x *= inv; vb.y *= inv; vb.z *= inv; vb.w *= inv;
        *(float4*)&L[lane * 8]     = va;
        *(float4*)&L[lane * 8 + 4] = vb;
    }
    __syncthreads();

    {
        const int head = lane >> 4;
        const float* hb = h_ws + (long)b * 512 * 64;
        float a0 = 0.f, a1 = 0.f, a2 = 0.f, a3 = 0.f;
        const int j0 = wave * 128;
        #pragma unroll 2
        for (int j = j0; j < j0 + 128; j += 4) {
            float4 c0 = *(const float4*)&coef[0][head][j];
            float4 c1 = *(const float4*)&coef[1][head][j];
            float4 c2 = *(const float4*)&coef[2][head][j];
            float4 c3 = *(const float4*)&coef[3][head][j];
            float h0v = hb[(long)(j + 0) * 64 + lane];
            float h1v = hb[(long)(j + 1) * 64 + lane];
            float h2v = hb[(long)(j + 2) * 64 + lane];
            float h3v = hb[(long)(j + 3) * 64 + lane];
            a0 = fmaf(h3v, c0.w, fmaf(h2v, c0.z, fmaf(h1v, c0.y, fmaf(h0v, c0.x, a0))));
            a1 = fmaf(h3v, c1.w, fmaf(h2v, c1.z, fmaf(h1v, c1.y, fmaf(h0v, c1.x, a1))));
            a2 = fmaf(h3v, c2.w, fmaf(h2v, c2.z, fmaf(h1v, c2.y, fmaf(h0v, c2.x, a2))));
            a3 = fmaf(h3v, c3.w, fmaf(h2v, c3.z, fmaf(h1v, c3.y, fmaf(h0v, c3.x, a3))));
        }
        hpart[wave][0][lane] = a0;
        hpart[wave][1][lane] = a1;
        hpart[wave][2][lane] = a2;
        hpart[wave][3][lane] = a3;
    }
    __syncthreads();

    {
        const int r   = wave;
        const int row = bi0 + r;
        float m = hpart[0][r][lane] + hpart[1][r][lane] + hpart[2][r][lane] + hpart[3][r][lane];
        msg_s[r][lane] = m;

        float o = bo[lane];
        const float* wrow = Wo + lane * 64;
        #pragma unroll
        for (int ff = 0; ff < 64; ++ff) o = fmaf(msg_s[r][ff], wrow[ff], o);
        o += node[(long)row * 64 + lane];
        o = (o > 0.f) ? o : 0.2f * o;
        float mu  = wave_sum64(o) * (1.0f / 64.0f);
        float d   = o - mu;
        float var = wave_sum64(d * d) * (1.0f / 64.0f);
        out[(long)row * 64 + lane] = d * rsqrtf(var + EPS) * lno_g[lane] + lno_b[lane];
    }
}

extern "C" void kernel_launch(void* const* d_in, const int* in_sizes, int n_in,
                              void* d_out, int out_size, void* d_ws, size_t ws_size,
                              hipStream_t stream) {
    const float* node   = (const float*)d_in[0];
    const float* edge   = (const float*)d_in[1];
    const int*   adj    = (const int*)  d_in[2];
    const float* ln1_g  = (const float*)d_in[3];
    const float* ln1_b  = (const float*)d_in[4];
    const float* Wn     = (const float*)d_in[5];
    const float* bn     = (const float*)d_in[6];
    const float* ln2_g  = (const float*)d_in[7];
    const float* ln2_b  = (const float*)d_in[8];
    const float* We1    = (const float*)d_in[9];
    const float* be1    = (const float*)d_in[10];
    const float* We2    = (const float*)d_in[11];
    const float* be2    = (const float*)d_in[12];
    const float* lne_g  = (const float*)d_in[13];
    const float* lne_b  = (const float*)d_in[14];
    const float* attn_A = (const float*)d_in[15];
    const float* Wo     = (const float*)d_in[16];
    const float* bo     = (const float*)d_in[17];
    const float* lno_g  = (const float*)d_in[18];
    const float* lno_b  = (const float*)d_in[19];

    float* out_p  = (float*)d_out;
    float* e_out  = out_p + 262144;
    float* adj_o  = e_out + 33554432;

    float* ws    = (float*)d_ws;
    float* h_ws  = ws;
    float* sr_ws = ws + 262144;
    float* sc_ws = ws + 278528;
    float* se_ws = ws + 294912;

    node_kernel<<<4096, 64, 0, stream>>>(node, ln1_g, ln1_b, Wn, bn, attn_A, h_ws, sr_ws, sc_ws);
    edge_kernel<<<8192, 256, 0, stream>>>(edge, adj, ln2_g, ln2_b, We1, be1, We2, be2,
                                          lne_g, lne_b, attn_A, e_out, adj_o, se_ws);
    attn_kernel<<<1024, 256, 0, stream>>>(h_ws, sr_ws, sc_ws, se_ws, adj, node,
                                          Wo, bo, lno_g, lno_b, out_p);
}

// Round 5
// 325.270 us; speedup vs baseline: 1.0096x; 1.0096x over previous
//
#include <hip/hip_runtime.h>

#define EPS 1e-5f

typedef __attribute__((ext_vector_type(8))) short bfrag;   // 8 bf16 = 4 VGPR (MFMA A/B)
typedef __attribute__((ext_vector_type(4))) float ffrag;   // 4 f32 (MFMA C/D)

union BFU { int i[4]; bfrag v; };

__device__ __forceinline__ float wave_sum64(float v) {
    #pragma unroll
    for (int off = 32; off > 0; off >>= 1) v += __shfl_xor(v, off, 64);
    return v;
}
__device__ __forceinline__ float wave_max64(float v) {
    #pragma unroll
    for (int off = 32; off > 0; off >>= 1) v = fmaxf(v, __shfl_xor(v, off, 64));
    return v;
}

// round-to-nearest-even f32 -> bf16, packed pair (proven bit-twiddle path)
__device__ __forceinline__ int pk_bf16(float a, float b) {
    union { float f; unsigned u; } x, y;
    x.f = a; y.f = b;
    unsigned ra = (x.u + 0x7fffu + ((x.u >> 16) & 1u)) >> 16;
    unsigned rb = (y.u + 0x7fffu + ((y.u >> 16) & 1u)) >> 16;
    return (int)((rb << 16) | (ra & 0xffffu));
}

// Sum across lanes {t, t+16, t+32, t+48} (the 4 quads) — proven shfl_xor path.
__device__ __forceinline__ float qsum(float v) {
    v += __shfl_xor(v, 16, 64);
    v += __shfl_xor(v, 32, 64);
    return v;
}

__device__ __forceinline__ float celu1(float x) {
    return (x > 0.f) ? x : (__expf(x) - 1.f);
}

// ---------------- Kernel 1: node branch + sr/sc ----------------
__global__ __launch_bounds__(64) void node_kernel(
    const float* __restrict__ node, const float* __restrict__ ln1_g, const float* __restrict__ ln1_b,
    const float* __restrict__ Wn, const float* __restrict__ bn, const float* __restrict__ attn_A,
    float* __restrict__ h_out, float* __restrict__ sr_out, float* __restrict__ sc_out)
{
    const int row  = blockIdx.x;
    const int lane = threadIdx.x;

    float x = node[(long)row * 64 + lane];
    float mu  = wave_sum64(x) * (1.0f / 64.0f);
    float d   = x - mu;
    float var = wave_sum64(d * d) * (1.0f / 64.0f);
    float xln = d * rsqrtf(var + EPS) * ln1_g[lane] + ln1_b[lane];

    __shared__ float xs[64];
    xs[lane] = xln;
    __syncthreads();

    float acc = bn[lane];
    const float* wrow = Wn + lane * 64;
    #pragma unroll
    for (int f = 0; f < 64; ++f) acc = fmaf(xs[f], wrow[f], acc);
    h_out[(long)row * 64 + lane] = acc;

    const int xidx = lane & 15;
    float ar = 0.f, ac = 0.f;
    #pragma unroll
    for (int hh = 0; hh < 4; ++hh) {
        ar += attn_A[hh * 48 + xidx];
        ac += attn_A[hh * 48 + 16 + xidx];
    }
    float pr = acc * ar, pc = acc * ac;
    #pragma unroll
    for (int off = 8; off > 0; off >>= 1) {
        pr += __shfl_down(pr, off, 16);
        pc += __shfl_down(pc, off, 16);
    }
    if (xidx == 0) {
        const int head = lane >> 4;
        sr_out[(long)row * 4 + head] = pr;
        sc_out[(long)row * 4 + head] = pc;
    }
}

// ---------------- Kernel 2: edge MLP via MFMA ----------------
// mfma_f32_16x16x32_bf16: A[m=lane&15][k=quad*8+j], B[k=quad*8+j][n=lane&15],
// D[m=quad*4+reg][n=lane&15].
//
// A1 row-permuted (We1 row 8*(m>>2)+(m&3)+4*mt) so lane (q,t)'s D1 regs hold
// hidden units 8q..8q+7 of row t == its own B2 fragment (no B2 gather).
//
// R5 changes vs the PROVEN R3 kernel (body kept verbatim):
//   - NT=8 tiles/wave (grid 4096): per-wave weight setup amortized 2x
//   - all 8 tile loads hoisted before the setup (setup's ~130 instrs cover
//     the HBM latency; loop body sees data already resident)
//   - adj passthrough (2 rows/lane) done right after setup
__global__ __launch_bounds__(256, 4) void edge_kernel(
    const float* __restrict__ edge, const int* __restrict__ adj,
    const float* __restrict__ ln2_g, const float* __restrict__ ln2_b,
    const float* __restrict__ We1, const float* __restrict__ be1,
    const float* __restrict__ We2, const float* __restrict__ be2,
    const float* __restrict__ lne_g, const float* __restrict__ lne_b,
    const float* __restrict__ attn_A,
    float* __restrict__ e_out, float* __restrict__ adj_out, float* __restrict__ se_out)
{
    const int tid  = threadIdx.x;
    const int wave = tid >> 6;
    const int lane = tid & 63;
    const int q    = lane >> 4;       // quad 0..3
    const int t    = lane & 15;
    const long r0  = (long)blockIdx.x * 512 + wave * 128;  // wave's 128 rows
    const int  c4  = 4 * q;           // this lane's channel chunk

    // ---- hoisted tile loads (latency covered by the setup below) ----
    float4 v[8];
    #pragma unroll
    for (int nt = 0; nt < 8; ++nt)
        v[nt] = *(const float4*)(edge + (r0 + 16 * nt + t) * 16 + c4);
    const int adv0 = adj[r0 + lane];
    const int adv1 = adj[r0 + 64 + lane];

    // ---- per-lane constants ----
    const float4 g1  = *(const float4*)(ln2_g + c4);
    const float4 b1  = *(const float4*)(ln2_b + c4);
    const float4 gE  = *(const float4*)(lne_g + c4);
    const float4 bE  = *(const float4*)(lne_b + c4);
    const float4 vb2 = *(const float4*)(be2 + c4);
    const float4 vb1a = *(const float4*)(be1 + 8 * q);      // hidden units 8q+reg   (acc0)
    const float4 vb1b = *(const float4*)(be1 + 8 * q + 4);  // hidden units 8q+4+reg (acc1)
    float4 ae = make_float4(0.f, 0.f, 0.f, 0.f);
    #pragma unroll
    for (int hh = 0; hh < 4; ++hh) {
        float4 a = *(const float4*)(attn_A + hh * 48 + 32 + c4);
        ae.x += a.x; ae.y += a.y; ae.z += a.z; ae.w += a.w;
    }

    // ---- weight fragments (loaded once, VGPR-resident) ----
    BFU A1[2], A2;
    A1[0].i[0] = A1[0].i[1] = A1[0].i[2] = A1[0].i[3] = 0;
    A1[1].i[0] = A1[1].i[1] = A1[1].i[2] = A1[1].i[3] = 0;
    if (q < 2) {   // K=16 zero-padded to 32: quads 2,3 stay zero
        const int rr = 8 * (t >> 2) + (t & 3);   // permuted We1 row for A-row m=t
        #pragma unroll
        for (int mt = 0; mt < 2; ++mt) {
            const float* wp = We1 + (rr + 4 * mt) * 16 + 8 * q;
            float4 w0 = *(const float4*)(wp);
            float4 w1 = *(const float4*)(wp + 4);
            A1[mt].i[0] = pk_bf16(w0.x, w0.y);
            A1[mt].i[1] = pk_bf16(w0.z, w0.w);
            A1[mt].i[2] = pk_bf16(w1.x, w1.y);
            A1[mt].i[3] = pk_bf16(w1.z, w1.w);
        }
    }
    {
        const float* wp = We2 + t * 32 + 8 * q;
        float4 w0 = *(const float4*)(wp);
        float4 w1 = *(const float4*)(wp + 4);
        A2.i[0] = pk_bf16(w0.x, w0.y);
        A2.i[1] = pk_bf16(w0.z, w0.w);
        A2.i[2] = pk_bf16(w1.x, w1.y);
        A2.i[3] = pk_bf16(w1.z, w1.w);
    }

    // adj passthrough: two rows per lane (independent of the MLP path)
    adj_out[r0 + lane]      = (float)adv0;
    adj_out[r0 + 64 + lane] = (float)adv1;

    const int srcA = ((q & 1) << 5) + t;   // B1 gather sources
    const int srcB = srcA + 16;

    #pragma unroll
    for (int nt = 0; nt < 8; ++nt) {
        const long R = r0 + 16 * nt + t;          // this lane's row for tile nt
        const float4 vv = v[nt];

        // LN over E=16 (row spread across 4 quads, 4 vals each)
        float s1 = vv.x + vv.y + vv.z + vv.w;
        float s2 = fmaf(vv.x, vv.x, fmaf(vv.y, vv.y, fmaf(vv.z, vv.z, vv.w * vv.w)));
        s1 = qsum(s1);
        s2 = qsum(s2);
        const float mu = s1 * (1.0f / 16.0f);
        float var = fmaxf(s2 * (1.0f / 16.0f) - mu * mu, 0.f);
        const float rs = rsqrtf(var + EPS);
        const float x0 = (vv.x - mu) * rs * g1.x + b1.x;
        const float x1 = (vv.y - mu) * rs * g1.y + b1.y;
        const float x2 = (vv.z - mu) * rs * g1.z + b1.z;
        const float x3 = (vv.w - mu) * rs * g1.w + b1.w;
        const int p0 = pk_bf16(x0, x1), p1 = pk_bf16(x2, x3);

        // B1 fragment: B[k=8q+j][n=t] = xln[row 16nt+t][ch 8q+j] (k>=16 -> A1=0)
        BFU B1;
        B1.i[0] = __shfl(p0, srcA, 64);
        B1.i[1] = __shfl(p1, srcA, 64);
        B1.i[2] = __shfl(p0, srcB, 64);
        B1.i[3] = __shfl(p1, srcB, 64);

        ffrag acc0 = { vb1a.x, vb1a.y, vb1a.z, vb1a.w };   // bias in C (permuted units)
        ffrag acc1 = { vb1b.x, vb1b.y, vb1b.z, vb1b.w };
        acc0 = __builtin_amdgcn_mfma_f32_16x16x32_bf16(A1[0].v, B1.v, acc0, 0, 0, 0);
        acc1 = __builtin_amdgcn_mfma_f32_16x16x32_bf16(A1[1].v, B1.v, acc1, 0, 0, 0);

        // celu + pack: lane holds units 8q..8q+7 of row t == its own B2 fragment
        BFU B2;
        B2.i[0] = pk_bf16(celu1(acc0[0]), celu1(acc0[1]));   // units 8q+0,1
        B2.i[1] = pk_bf16(celu1(acc0[2]), celu1(acc0[3]));   // units 8q+2,3
        B2.i[2] = pk_bf16(celu1(acc1[0]), celu1(acc1[1]));   // units 8q+4,5
        B2.i[3] = pk_bf16(celu1(acc1[2]), celu1(acc1[3]));   // units 8q+6,7

        ffrag acc2 = { vb2.x, vb2.y, vb2.z, vb2.w };
        acc2 = __builtin_amdgcn_mfma_f32_16x16x32_bf16(A2.v, B2.v, acc2, 0, 0, 0);

        // residual + final LN + se
        const float o0 = acc2[0] + vv.x;
        const float o1 = acc2[1] + vv.y;
        const float o2 = acc2[2] + vv.z;
        const float o3 = acc2[3] + vv.w;
        float m1 = o0 + o1 + o2 + o3;
        float m2 = fmaf(o0, o0, fmaf(o1, o1, fmaf(o2, o2, o3 * o3)));
        m1 = qsum(m1);
        m2 = qsum(m2);
        const float mu2 = m1 * (1.0f / 16.0f);
        float var2 = fmaxf(m2 * (1.0f / 16.0f) - mu2 * mu2, 0.f);
        const float rs2 = rsqrtf(var2 + EPS);
        const float e0 = (o0 - mu2) * rs2 * gE.x + bE.x;
        const float e1 = (o1 - mu2) * rs2 * gE.y + bE.y;
        const float e2 = (o2 - mu2) * rs2 * gE.z + bE.z;
        const float e3 = (o3 - mu2) * rs2 * gE.w + bE.w;

        *(float4*)(e_out + R * 16 + c4) = make_float4(e0, e1, e2, e3);

        float sep = fmaf(e0, ae.x, fmaf(e1, ae.y, fmaf(e2, ae.z, e3 * ae.w)));
        sep = qsum(sep);
        if (q == 0) se_out[R] = sep;
    }
}

// ---------------- Kernel 3: attention softmax + msg + output proj + LN ----------------
#define G 4
__global__ __launch_bounds__(256, 4) void attn_kernel(
    const float* __restrict__ h_ws, const float* __restrict__ sr_ws, const float* __restrict__ sc_ws,
    const float* __restrict__ se_ws, const int* __restrict__ adj,
    const float* __restrict__ node, const float* __restrict__ Wo, const float* __restrict__ bo,
    const float* __restrict__ lno_g, const float* __restrict__ lno_b,
    float* __restrict__ out)
{
    const int bi0  = blockIdx.x * G;
    const int b    = bi0 >> 9;
    const int tid  = threadIdx.x;
    const int wave = tid >> 6;
    const int lane = tid & 63;

    __shared__ __align__(16) float coef[G][4][516];
    __shared__ float hpart[4][G][64];
    __shared__ float msg_s[G][64];

    const float4* sc4 = (const float4*)(sc_ws + (long)b * 512 * 4);

    #pragma unroll
    for (int r = 0; r < G; ++r) {
        const int row = bi0 + r;
        const float sr0 = sr_ws[(long)row * 4 + 0];
        const float sr1 = sr_ws[(long)row * 4 + 1];
        const float sr2 = sr_ws[(long)row * 4 + 2];
        const float sr3 = sr_ws[(long)row * 4 + 3];
        const float* se_row  = se_ws + (long)row * 512;
        const int*   adj_row = adj   + (long)row * 512;
        #pragma unroll
        for (int half = 0; half < 2; ++half) {
            const int j = half * 256 + tid;
            float4 s = sc4[j];
            float  se = se_row[j];
            bool   m  = (adj_row[j] != 0);
            float l0 = m ? (sr0 + s.x + se) : -1e9f;
            float l1 = m ? (sr1 + s.y + se) : -1e9f;
            float l2 = m ? (sr2 + s.z + se) : -1e9f;
            float l3 = m ? (sr3 + s.w + se) : -1e9f;
            l0 = (l0 > 0.f) ? l0 : 0.2f * l0;  l0 = fminf(fmaxf(l0, -1e9f), 1e9f);
            l1 = (l1 > 0.f) ? l1 : 0.2f * l1;  l1 = fminf(fmaxf(l1, -1e9f), 1e9f);
            l2 = (l2 > 0.f) ? l2 : 0.2f * l2;  l2 = fminf(fmaxf(l2, -1e9f), 1e9f);
            l3 = (l3 > 0.f) ? l3 : 0.2f * l3;  l3 = fminf(fmaxf(l3, -1e9f), 1e9f);
            coef[r][0][j] = l0; coef[r][1][j] = l1; coef[r][2][j] = l2; coef[r][3][j] = l3;
        }
    }
    __syncthreads();

    // softmax: each lane owns a contiguous 8-float chunk -> 4 ds_read_b128 / lane
    #pragma unroll
    for (int qq = 0; qq < 4; ++qq) {
        const int p = qq * 4 + wave;
        float* L = coef[p >> 2][p & 3];
        float4 va = *(const float4*)&L[lane * 8];
        float4 vb = *(const float4*)&L[lane * 8 + 4];
        float m = fmaxf(fmaxf(fmaxf(va.x, va.y), fmaxf(va.z, va.w)),
                        fmaxf(fmaxf(vb.x, vb.y), fmaxf(vb.z, vb.w)));
        m = wave_max64(m);
        va.x = __expf(va.x - m); va.y = __expf(va.y - m);
        va.z = __expf(va.z - m); va.w = __expf(va.w - m);
        vb.x = __expf(vb.x - m); vb.y = __expf(vb.y - m);
        vb.z = __expf(vb.z - m); vb.w = __expf(vb.w - m);
        float s = (va.x + va.y + va.z + va.w) + (vb.x + vb.y + vb.z + vb.w);
        s = wave_sum64(s);
        const float inv = 1.0f / s;
        va.x *= inv; va.y *= inv; va.z *= inv; va.w *= inv;
        vb.x *= inv; vb.y *= inv; vb.z *= inv; vb.w *= inv;
        *(float4*)&L[lane * 8]     = va;
        *(float4*)&L[lane * 8 + 4] = vb;
    }
    __syncthreads();

    {
        const int head = lane >> 4;
        const float* hb = h_ws + (long)b * 512 * 64;
        float a0 = 0.f, a1 = 0.f, a2 = 0.f, a3 = 0.f;
        const int j0 = wave * 128;
        #pragma unroll 2
        for (int j = j0; j < j0 + 128; j += 4) {
            float4 c0 = *(const float4*)&coef[0][head][j];
            float4 c1 = *(const float4*)&coef[1][head][j];
            float4 c2 = *(const float4*)&coef[2][head][j];
            float4 c3 = *(const float4*)&coef[3][head][j];
            float h0v = hb[(long)(j + 0) * 64 + lane];
            float h1v = hb[(long)(j + 1) * 64 + lane];
            float h2v = hb[(long)(j + 2) * 64 + lane];
            float h3v = hb[(long)(j + 3) * 64 + lane];
            a0 = fmaf(h3v, c0.w, fmaf(h2v, c0.z, fmaf(h1v, c0.y, fmaf(h0v, c0.x, a0))));
            a1 = fmaf(h3v, c1.w, fmaf(h2v, c1.z, fmaf(h1v, c1.y, fmaf(h0v, c1.x, a1))));
            a2 = fmaf(h3v, c2.w, fmaf(h2v, c2.z, fmaf(h1v, c2.y, fmaf(h0v, c2.x, a2))));
            a3 = fmaf(h3v, c3.w, fmaf(h2v, c3.z, fmaf(h1v, c3.y, fmaf(h0v, c3.x, a3))));
        }
        hpart[wave][0][lane] = a0;
        hpart[wave][1][lane] = a1;
        hpart[wave][2][lane] = a2;
        hpart[wave][3][lane] = a3;
    }
    __syncthreads();

    {
        const int r   = wave;
        const int row = bi0 + r;
        float m = hpart[0][r][lane] + hpart[1][r][lane] + hpart[2][r][lane] + hpart[3][r][lane];
        msg_s[r][lane] = m;

        float o = bo[lane];
        const float* wrow = Wo + lane * 64;
        #pragma unroll
        for (int ff = 0; ff < 64; ++ff) o = fmaf(msg_s[r][ff], wrow[ff], o);
        o += node[(long)row * 64 + lane];
        o = (o > 0.f) ? o : 0.2f * o;
        float mu  = wave_sum64(o) * (1.0f / 64.0f);
        float d   = o - mu;
        float var = wave_sum64(d * d) * (1.0f / 64.0f);
        out[(long)row * 64 + lane] = d * rsqrtf(var + EPS) * lno_g[lane] + lno_b[lane];
    }
}

extern "C" void kernel_launch(void* const* d_in, const int* in_sizes, int n_in,
                              void* d_out, int out_size, void* d_ws, size_t ws_size,
                              hipStream_t stream) {
    const float* node   = (const float*)d_in[0];
    const float* edge   = (const float*)d_in[1];
    const int*   adj    = (const int*)  d_in[2];
    const float* ln1_g  = (const float*)d_in[3];
    const float* ln1_b  = (const float*)d_in[4];
    const float* Wn     = (const float*)d_in[5];
    const float* bn     = (const float*)d_in[6];
    const float* ln2_g  = (const float*)d_in[7];
    const float* ln2_b  = (const float*)d_in[8];
    const float* We1    = (const float*)d_in[9];
    const float* be1    = (const float*)d_in[10];
    const float* We2    = (const float*)d_in[11];
    const float* be2    = (const float*)d_in[12];
    const float* lne_g  = (const float*)d_in[13];
    const float* lne_b  = (const float*)d_in[14];
    const float* attn_A = (const float*)d_in[15];
    const float* Wo     = (const float*)d_in[16];
    const float* bo     = (const float*)d_in[17];
    const float* lno_g  = (const float*)d_in[18];
    const float* lno_b  = (const float*)d_in[19];

    float* out_p  = (float*)d_out;
    float* e_out  = out_p + 262144;
    float* adj_o  = e_out + 33554432;

    float* ws    = (float*)d_ws;
    float* h_ws  = ws;
    float* sr_ws = ws + 262144;
    float* sc_ws = ws + 278528;
    float* se_ws = ws + 294912;

    node_kernel<<<4096, 64, 0, stream>>>(node, ln1_g, ln1_b, Wn, bn, attn_A, h_ws, sr_ws, sc_ws);
    edge_kernel<<<4096, 256, 0, stream>>>(edge, adj, ln2_g, ln2_b, We1, be1, We2, be2,
                                          lne_g, lne_b, attn_A, e_out, adj_o, se_ws);
    attn_kernel<<<1024, 256, 0, stream>>>(h_ws, sr_ws, sc_ws, se_ws, adj, node,
                                          Wo, bo, lno_g, lno_b, out_p);
}